// Round 8
// baseline (803.601 us; speedup 1.0000x reference)
//
#include <hip/hip_runtime.h>
#include <cfloat>

// Problem: B=16,N=2048,D=512 tokens vs K=8192 codebook; out = codebook[argmin dist]
#define TOKENS 32768
#define DDIM   512
#define KCODES 8192

#define CAP    160        // candidate list capacity per token
#define MARGIN 2.0f       // >> 2*max bf16 score error (~0.6 max, 0.072 std)

// ---- workspace layout (bytes) ----
#define ZEBF_OFF   0                                   // bf16 ze  [32768][512]
#define CBBF_OFF   (TOKENS * DDIM * 2)                 // bf16 cb  [8192][512]
#define CNORM_OFF  (CBBF_OFF + KCODES * DDIM * 2)      // fp32 ||c||^2 [8192]
#define CNT_OFF    (CNORM_OFF + KCODES * 4)            // int   cnt [32768]
#define CANDI_OFF  (CNT_OFF + TOKENS * 4)              // int   cand idx [32768][CAP]
#define CANDS_OFF  (CANDI_OFF + TOKENS * CAP * 4)      // float cand s~  [32768][CAP]
#define WS_REQ     ((size_t)(CANDS_OFF + TOKENS * CAP * 4))   // 84,049,920 B

typedef short bf16x8 __attribute__((ext_vector_type(8)));   // 8 bf16 (4 VGPRs)
typedef float f32x4  __attribute__((ext_vector_type(4)));

// async global->LDS, 16B per lane; LDS dest must be wave-uniform base + lane*16
__device__ __forceinline__ void gld16(const void* g, void* l) {
    __builtin_amdgcn_global_load_lds(
        (const __attribute__((address_space(1))) void*)g,
        (__attribute__((address_space(3))) void*)l,
        16, 0, 0);
}

// R8: raw s_barrier is NOT a compiler memory fence (IntrNoMem-class) — the
// scheduler may float ds_read / gld16 across it (rule #18 class; m152 races).
// Pin program order with sched_barrier(0) on both sides. Zero runtime cost.
__device__ __forceinline__ void fence_barrier() {
    __builtin_amdgcn_sched_barrier(0);
    __builtin_amdgcn_s_barrier();
    __builtin_amdgcn_sched_barrier(0);
}

__device__ __forceinline__ unsigned short f2bf(float f) {
    union { float f; unsigned int u; } v; v.f = f;
    unsigned int u = v.u;
    return (unsigned short)((u + 0x7fffu + ((u >> 16) & 1u)) >> 16);  // RNE
}

// ---- fp32 -> bf16 conversion (8 elems/thread) -------------------------------
__global__ __launch_bounds__(256) void convert_kernel(const float* __restrict__ src,
                                                      unsigned short* __restrict__ dst,
                                                      int n8) {
    int i = blockIdx.x * 256 + threadIdx.x;
    if (i >= n8) return;
    float4 a = ((const float4*)src)[i * 2];
    float4 b = ((const float4*)src)[i * 2 + 1];
    bf16x8 o;
    o[0] = (short)f2bf(a.x); o[1] = (short)f2bf(a.y);
    o[2] = (short)f2bf(a.z); o[3] = (short)f2bf(a.w);
    o[4] = (short)f2bf(b.x); o[5] = (short)f2bf(b.y);
    o[6] = (short)f2bf(b.z); o[7] = (short)f2bf(b.w);
    *(bf16x8*)&dst[(size_t)i * 8] = o;
}

// ---- codebook row squared norms (fp32, exact) -------------------------------
__global__ __launch_bounds__(256) void cnorm_kernel(const float* __restrict__ cb,
                                                    float* __restrict__ cnorm) {
    int row  = blockIdx.x * 4 + (threadIdx.x >> 6);
    int lane = threadIdx.x & 63;
    const float* r = cb + (size_t)row * DDIM;
    float s = 0.f;
    #pragma unroll
    for (int d = lane; d < DDIM; d += 64) { float v = r[d]; s += v * v; }
    #pragma unroll
    for (int off = 32; off > 0; off >>= 1) s += __shfl_down(s, off, 64);
    if (lane == 0) cnorm[row] = s;
}

// ---- main: bf16 MFMA scores + margin candidate collection -------------------
// R8 = R6 ring + sched_barrier(0) fences (R7 failed absmax 4.48: compiler
// reordering across raw s_barrier / inline-asm waits — rule #18 / m152 class).
// Geometry (R5, HW-verified): 128 tok x 128 codes, 4 waves 2x2, wave 64x64,
// acc[4][4] = 64 AGPR, ~(72+64) regs -> (256,3): 3 blk/CU.
// DEPTH-2 prefetch, BK=32, 3-buffer LDS ring:
//   prologue: STAGE(b0,c0); STAGE(b1,c1)
//   iter t:   STAGE(b[(t+2)%3], t+2); vmcnt(8) [chunk t landed, t+1/t+2 in
//             flight]; fenced barrier; COMPUTE(b[t%3]) 16 MFMA; fenced barrier
//   tail: vmcnt(4) ... vmcnt(0) peeled with literal immediates.
// Ring audit: buf (t+2)%3 was last read at iter t-1, sealed by that iter's
// closing barrier before this STAGE issues; per-wave vmcnt + barrier makes all
// waves' chunk-t loads visible before COMPUTE reads them.
// LDS = 3*(8K A + 8K B) + 1K smin = ~49 KB -> 3 blk/CU preserved.
// Swizzle phys_slot = slot ^ ((row>>1)&3): HW-verified in R4 (absmax 0,
// SQ_LDS_BANK_CONFLICT = 0).
//
// Block scheduling (L2 locality): 1-D grid of 16384 blocks, decomposed as
//   xcd      = bid & 7          (round-robin XCD heuristic)
//   panel    = (bid>>3) >> 8    cb panel of 1024 codes (1 MB bf16, L2-resident)
//   tb_local = ((bid>>3)&255)>>3, cb_local = (bid>>3)&7  (codes iterate fastest)
__global__ __launch_bounds__(256, 3) void vq_mfma_kernel(
        const unsigned short* __restrict__ zebf,
        const unsigned short* __restrict__ cbbf,
        const float* __restrict__ cnorm,
        int* __restrict__ cnt,
        int* __restrict__ candI,
        float* __restrict__ candS) {
    // LDS rows of 32 bf16 (64 B = 4 slots of 16 B), XOR-swizzled on the
    // global source side (gld16 LDS dest stays linear).
    __shared__ unsigned short Ab[3][128 * 32];   // 3 x 8 KB (tokens x 32 dims)
    __shared__ unsigned short Bb[3][128 * 32];   // 3 x 8 KB (codes  x 32 dims)
    __shared__ float smin[2][128];               // [wc][token_local] cross-wave min

    const int tid  = threadIdx.x;
    const int w    = tid >> 6;
    const int lane = tid & 63;
    const int wr   = w >> 1;          // token half 0..1
    const int wc   = w & 1;           // code  half 0..1

    const int bid      = blockIdx.x;
    const int xcd      = bid & 7;
    const int loc      = bid >> 3;        // 0..2047
    const int panel    = loc >> 8;        // 0..7
    const int l2i      = loc & 255;
    const int tb_local = l2i >> 3;        // 0..31
    const int cb_local = l2i & 7;         // 0..7
    const int token_blk = tb_local * 8 + xcd;     // 0..255
    const int code_blk  = panel * 8 + cb_local;   // 0..63

    const int tok0  = token_blk * 128;
    const int code0 = code_blk * 128;

    // ---- hoisted staging offsets: 2 A + 2 B gld16 per thread per chunk ----
    int ldsOff[2], offA[2], offB[2];
    #pragma unroll
    for (int p = 0; p < 2; ++p) {
        int L    = p * 4096 + tid * 16;   // byte offset in 8 KB buffer, wave-contig
        int row  = L >> 6;                // 64 B per LDS row (32 bf16)
        int phys = (L >> 4) & 3;
        int slog = phys ^ ((row >> 1) & 3);
        ldsOff[p] = L;
        offA[p] = (tok0  + row) * DDIM + slog * 8;   // element offsets (dk added)
        offB[p] = (code0 + row) * DDIM + slog * 8;
    }

    // ---- hoisted fragment element offsets (K=32: slot s0 = lane>>4) ----
    const int s0 = lane >> 4;
    int aOff[4], bOff[4];
    #pragma unroll
    for (int rt = 0; rt < 4; ++rt) {
        int row  = wr * 64 + rt * 16 + (lane & 15);
        aOff[rt] = row * 32 + (s0 ^ ((row >> 1) & 3)) * 8;
    }
    #pragma unroll
    for (int ct = 0; ct < 4; ++ct) {
        int row  = wc * 64 + ct * 16 + (lane & 15);
        bOff[ct] = row * 32 + (s0 ^ ((row >> 1) & 3)) * 8;
    }

    f32x4 acc[4][4];
    const f32x4 zero = {0.f, 0.f, 0.f, 0.f};
    #pragma unroll
    for (int i = 0; i < 4; ++i)
        #pragma unroll
        for (int j = 0; j < 4; ++j) acc[i][j] = zero;

    auto STAGE = [&](int buf, int ck) {
        int dk = ck * 32;
        #pragma unroll
        for (int p = 0; p < 2; ++p) {
            gld16(zebf + (size_t)(offA[p] + dk), (char*)Ab[buf] + ldsOff[p]);
            gld16(cbbf + (size_t)(offB[p] + dk), (char*)Bb[buf] + ldsOff[p]);
        }
    };

    auto COMPUTE = [&](int buf) {
        const unsigned short* A = Ab[buf];
        const unsigned short* B = Bb[buf];
        bf16x8 af[4], bfr[4];
        #pragma unroll
        for (int rt = 0; rt < 4; ++rt) af[rt]  = *(const bf16x8*)(A + aOff[rt]);
        #pragma unroll
        for (int ct = 0; ct < 4; ++ct) bfr[ct] = *(const bf16x8*)(B + bOff[ct]);
        #pragma unroll
        for (int rt = 0; rt < 4; ++rt)
            #pragma unroll
            for (int ct = 0; ct < 4; ++ct)
                acc[rt][ct] = __builtin_amdgcn_mfma_f32_16x16x32_bf16(
                    af[rt], bfr[ct], acc[rt][ct], 0, 0, 0);
    };

    const int NCHUNK = DDIM / 32;   // 16

    STAGE(0, 0);
    STAGE(1, 1);
    #pragma unroll 1
    for (int t = 0; t < NCHUNK - 2; ++t) {
        STAGE((t + 2) % 3, t + 2);                        // depth-2 prefetch
        __builtin_amdgcn_sched_barrier(0);                // pin: stage stays above wait
        asm volatile("s_waitcnt vmcnt(8)" ::: "memory");  // chunk t landed; 8 flying
        __builtin_amdgcn_sched_barrier(0);                // rule #18: fence after wait
        fence_barrier();                                  // all waves' stage visible
        COMPUTE(t % 3);
        fence_barrier();                                  // reads done before reuse
    }
    // t = NCHUNK-2: nothing left to stage; chunks 14,15 in flight
    asm volatile("s_waitcnt vmcnt(4)" ::: "memory");
    __builtin_amdgcn_sched_barrier(0);
    fence_barrier();
    COMPUTE((NCHUNK - 2) % 3);
    fence_barrier();
    // t = NCHUNK-1
    asm volatile("s_waitcnt vmcnt(0)" ::: "memory");
    __builtin_amdgcn_sched_barrier(0);
    fence_barrier();
    COMPUTE((NCHUNK - 1) % 3);

    // ---- epilogue: C/D layout col=lane&15, row=(lane>>4)*4+reg ----
    float cn[4];
    #pragma unroll
    for (int ct = 0; ct < 4; ++ct)
        cn[ct] = cnorm[code0 + wc * 64 + ct * 16 + (lane & 15)];

    // per-wave rowmin over its 64 codes; publish for cross-wave combine
    float rm[4][4];
    #pragma unroll
    for (int rt = 0; rt < 4; ++rt)
        #pragma unroll
        for (int r = 0; r < 4; ++r) {
            float m = cn[0] - 2.f * acc[rt][0][r];
            #pragma unroll
            for (int ct = 1; ct < 4; ++ct)
                m = fminf(m, cn[ct] - 2.f * acc[rt][ct][r]);
            #pragma unroll
            for (int off = 1; off < 16; off <<= 1)
                m = fminf(m, __shfl_xor(m, off, 64));
            rm[rt][r] = m;
            if ((lane & 15) == 0)
                smin[wc][wr * 64 + rt * 16 + (lane >> 4) * 4 + r] = m;
        }
    __syncthreads();

    #pragma unroll
    for (int rt = 0; rt < 4; ++rt)
        #pragma unroll
        for (int r = 0; r < 4; ++r) {
            int tl = wr * 64 + rt * 16 + (lane >> 4) * 4 + r;
            float mo  = smin[1 - wc][tl];               // other code-half's rowmin
            float thr = fminf(rm[rt][r], mo) + MARGIN;  // true 128-code block min
            int token = tok0 + tl;
            #pragma unroll
            for (int ct = 0; ct < 4; ++ct) {
                float s = cn[ct] - 2.f * acc[rt][ct][r];
                if (s <= thr) {
                    int pos = atomicAdd(&cnt[token], 1);
                    if (pos < CAP) {
                        candI[(size_t)token * CAP + pos] = code0 + wc * 64 + ct * 16 + (lane & 15);
                        candS[(size_t)token * CAP + pos] = s;
                    }
                }
            }
        }
}

// ---- exact fp32 rescore of survivors + gather (4 waves per token) -----------
// Candidates split across 4 waves; per-wave (best,idx) combined via LDS with
// the same lexicographic (s, then idx) tie-break.
__global__ __launch_bounds__(256) void rescore_kernel(
        const float* __restrict__ ze, const float* __restrict__ cb,
        const float* __restrict__ cnorm, const int* __restrict__ cnt,
        const int* __restrict__ candI, const float* __restrict__ candS,
        float* __restrict__ out) {
    const int t    = blockIdx.x;
    const int tid  = threadIdx.x;
    const int v    = tid >> 6;      // wave 0..3
    const int lane = tid & 63;

    __shared__ float sbest[4];
    __shared__ int   sidx[4];

    float4 za = *(const float4*)&ze[(size_t)t * DDIM + lane * 8];
    float4 zb = *(const float4*)&ze[(size_t)t * DDIM + lane * 8 + 4];

    int n = cnt[t];
    bool ovf = (n > CAP) || (n <= 0);

    float best = FLT_MAX;
    int   bidx = 0x7fffffff;

    if (!ovf) {
        // m~ = global min of s~ (every block's true min is in the list);
        // computed redundantly per wave (<= 3 strided passes, cheap).
        float m = FLT_MAX;
        for (int e = lane; e < n; e += 64)
            m = fminf(m, candS[(size_t)t * CAP + e]);
        #pragma unroll
        for (int off = 32; off > 0; off >>= 1)
            m = fminf(m, __shfl_xor(m, off, 64));
        float thr = m + MARGIN;

        for (int base = v * 64; base < n; base += 256) {
            int e = base + lane;
            int myI = 0; float sv = FLT_MAX;
            if (e < n) { myI = candI[(size_t)t * CAP + e]; sv = candS[(size_t)t * CAP + e]; }
            unsigned long long mask = __ballot(e < n && sv <= thr);
            while (mask) {
                int b = __ffsll((long long)mask) - 1;
                mask &= mask - 1;
                int code = __shfl(myI, b, 64);
                const float* row = cb + (size_t)code * DDIM + lane * 8;
                float4 ca = *(const float4*)row;
                float4 cc = *(const float4*)(row + 4);
                float d = za.x*ca.x + za.y*ca.y + za.z*ca.z + za.w*ca.w
                        + zb.x*cc.x + zb.y*cc.y + zb.z*cc.z + zb.w*cc.w;
                #pragma unroll
                for (int off = 32; off > 0; off >>= 1) d += __shfl_xor(d, off, 64);
                float s = cnorm[code] - 2.f * d;
                if (s < best || (s == best && code < bidx)) { best = s; bidx = code; }
            }
        }
    } else {
        for (int code = v; code < KCODES; code += 4) {
            const float* row = cb + (size_t)code * DDIM + lane * 8;
            float4 ca = *(const float4*)row;
            float4 cc = *(const float4*)(row + 4);
            float d = za.x*ca.x + za.y*ca.y + za.z*ca.z + za.w*ca.w
                    + zb.x*cc.x + zb.y*cc.y + zb.z*cc.z + zb.w*cc.w;
            #pragma unroll
            for (int off = 32; off > 0; off >>= 1) d += __shfl_xor(d, off, 64);
            float s = cnorm[code] - 2.f * d;
            if (s < best || (s == best && code < bidx)) { best = s; bidx = code; }
        }
    }

    if (lane == 0) { sbest[v] = best; sidx[v] = bidx; }
    __syncthreads();

    float fb = sbest[0]; int fi = sidx[0];
    #pragma unroll
    for (int k = 1; k < 4; ++k) {
        float s = sbest[k]; int ix = sidx[k];
        if (s < fb || (s == fb && ix < fi)) { fb = s; fi = ix; }
    }

    // gather winner row: 128 threads x float4 = 512 floats
    if (tid < 128) {
        float4 o = *(const float4*)&cb[(size_t)fi * DDIM + tid * 4];
        *(float4*)&out[(size_t)t * DDIM + tid * 4] = o;
    }
}

// ============================ R1 fallback path ===============================
#define TM 64
#define TN 64
#define BK 32
#define LDS_STRIDE (TM + 4)

__global__ __launch_bounds__(256) void vq_fallback_kernel(const float* __restrict__ ze,
                                                          const float* __restrict__ cb,
                                                          const float* __restrict__ cnorm,
                                                          float* __restrict__ out) {
    __shared__ float At[BK][LDS_STRIDE];
    __shared__ float Bt[BK][LDS_STRIDE];
    __shared__ float rv[TM][16];
    __shared__ int   ri[TM][16];
    __shared__ int   best_s[TM];

    const int tid = threadIdx.x;
    const int tx  = tid & 15;
    const int ty  = tid >> 4;
    const int token_base = blockIdx.x * TM;
    const int sc = tid & 31;
    const int sr = tid >> 5;

    float bestv[4] = {FLT_MAX, FLT_MAX, FLT_MAX, FLT_MAX};
    int   besti[4] = {0, 0, 0, 0};

    for (int ctile = 0; ctile < KCODES; ctile += TN) {
        float acc[4][4] = {{0.f}};
        for (int dk = 0; dk < DDIM; dk += BK) {
            __syncthreads();
            #pragma unroll
            for (int p = 0; p < 8; ++p) {
                int r = p * 8 + sr;
                At[sc][r] = ze[(size_t)(token_base + r) * DDIM + dk + sc];
                Bt[sc][r] = cb[(size_t)(ctile + r) * DDIM + dk + sc];
            }
            __syncthreads();
            #pragma unroll
            for (int d = 0; d < BK; ++d) {
                float a[4], b[4];
                *(float4*)a = *(const float4*)&At[d][ty * 4];
                *(float4*)b = *(const float4*)&Bt[d][tx * 4];
                #pragma unroll
                for (int i = 0; i < 4; ++i)
                    #pragma unroll
                    for (int j = 0; j < 4; ++j)
                        acc[i][j] += a[i] * b[j];
            }
        }
        #pragma unroll
        for (int j = 0; j < 4; ++j) {
            int code = ctile + tx * 4 + j;
            float cnv = cnorm[code];
            #pragma unroll
            for (int i = 0; i < 4; ++i) {
                float s = cnv - 2.f * acc[i][j];
                if (s < bestv[i]) { bestv[i] = s; besti[i] = code; }
            }
        }
    }
    #pragma unroll
    for (int i = 0; i < 4; ++i) {
        rv[ty * 4 + i][tx] = bestv[i];
        ri[ty * 4 + i][tx] = besti[i];
    }
    __syncthreads();
    if (tid < TM) {
        float bv = rv[tid][0]; int bi = ri[tid][0];
        #pragma unroll
        for (int x = 1; x < 16; ++x) {
            float v = rv[tid][x]; int ix = ri[tid][x];
            if (v < bv || (v == bv && ix < bi)) { bv = v; bi = ix; }
        }
        best_s[tid] = bi;
    }
    __syncthreads();
    const int gr   = tid >> 7;
    const int gcol = (tid & 127) * 4;
    for (int rr = 0; rr < TM; rr += 2) {
        int tk  = rr + gr;
        int src = best_s[tk];
        float4 v = *(const float4*)&cb[(size_t)src * DDIM + gcol];
        *(float4*)&out[(size_t)(token_base + tk) * DDIM + gcol] = v;
    }
}

extern "C" void kernel_launch(void* const* d_in, const int* in_sizes, int n_in,
                              void* d_out, int out_size, void* d_ws, size_t ws_size,
                              hipStream_t stream) {
    const float* ze = (const float*)d_in[0];   // [32768][512]
    const float* cb = (const float*)d_in[1];   // [8192][512]
    float* out      = (float*)d_out;

    if (ws_size < WS_REQ) {
        // not enough scratch for the MFMA pipeline: R1 exact-fp32 path
        float* cnorm = (float*)d_ws;
        cnorm_kernel<<<KCODES / 4, 256, 0, stream>>>(cb, cnorm);
        vq_fallback_kernel<<<TOKENS / TM, 256, 0, stream>>>(ze, cb, cnorm, out);
        return;
    }

    char* ws = (char*)d_ws;
    unsigned short* zebf = (unsigned short*)(ws + ZEBF_OFF);
    unsigned short* cbbf = (unsigned short*)(ws + CBBF_OFF);
    float* cnorm = (float*)(ws + CNORM_OFF);
    int*   cnt   = (int*)(ws + CNT_OFF);
    int*   candI = (int*)(ws + CANDI_OFF);
    float* candS = (float*)(ws + CANDS_OFF);

    convert_kernel<<<(TOKENS * DDIM / 8) / 256, 256, 0, stream>>>(ze, zebf, TOKENS * DDIM / 8);
    convert_kernel<<<(KCODES * DDIM / 8) / 256, 256, 0, stream>>>(cb, cbbf, KCODES * DDIM / 8);
    cnorm_kernel<<<KCODES / 4, 256, 0, stream>>>(cb, cnorm);
    hipMemsetAsync(cnt, 0, TOKENS * sizeof(int), stream);

    // 1-D grid; block->tile mapping (panel/XCD swizzle) computed in-kernel
    vq_mfma_kernel<<<(TOKENS / 128) * (KCODES / 128), 256, 0, stream>>>(
        zebf, cbbf, cnorm, cnt, candI, candS);

    rescore_kernel<<<TOKENS, 256, 0, stream>>>(ze, cb, cnorm, cnt, candI, candS, out);
}

// Round 10
// 698.545 us; speedup vs baseline: 1.1504x; 1.1504x over previous
//
#include <hip/hip_runtime.h>
#include <cfloat>

// Problem: B=16,N=2048,D=512 tokens vs K=8192 codebook; out = codebook[argmin dist]
#define TOKENS 32768
#define DDIM   512
#define KCODES 8192

#define CAP    160        // candidate list capacity per token
#define MARGIN 2.0f       // >> 2*max bf16 score error (~0.6 max, 0.072 std)

// ---- workspace layout (bytes) ----
#define ZEBF_OFF   0                                   // bf16 ze  [32768][512]
#define CBBF_OFF   (TOKENS * DDIM * 2)                 // bf16 cb  [8192][512]
#define CNORM_OFF  (CBBF_OFF + KCODES * DDIM * 2)      // fp32 ||c||^2 [8192]
#define CNT_OFF    (CNORM_OFF + KCODES * 4)            // int   cnt [32768]
#define CANDI_OFF  (CNT_OFF + TOKENS * 4)              // int   cand idx [32768][CAP]
#define CANDS_OFF  (CANDI_OFF + TOKENS * CAP * 4)      // float cand s~  [32768][CAP]
#define WS_REQ     ((size_t)(CANDS_OFF + TOKENS * CAP * 4))   // 84,049,920 B

typedef short bf16x8 __attribute__((ext_vector_type(8)));   // 8 bf16 (4 VGPRs)
typedef float f32x4  __attribute__((ext_vector_type(4)));

// async global->LDS, 16B per lane; LDS dest must be wave-uniform base + lane*16
__device__ __forceinline__ void gld16(const void* g, void* l) {
    __builtin_amdgcn_global_load_lds(
        (const __attribute__((address_space(1))) void*)g,
        (__attribute__((address_space(3))) void*)l,
        16, 0, 0);
}

__device__ __forceinline__ unsigned short f2bf(float f) {
    union { float f; unsigned int u; } v; v.f = f;
    unsigned int u = v.u;
    return (unsigned short)((u + 0x7fffu + ((u >> 16) & 1u)) >> 16);  // RNE
}

// ---- fp32 -> bf16 conversion (8 elems/thread) -------------------------------
__global__ __launch_bounds__(256) void convert_kernel(const float* __restrict__ src,
                                                      unsigned short* __restrict__ dst,
                                                      int n8) {
    int i = blockIdx.x * 256 + threadIdx.x;
    if (i >= n8) return;
    float4 a = ((const float4*)src)[i * 2];
    float4 b = ((const float4*)src)[i * 2 + 1];
    bf16x8 o;
    o[0] = (short)f2bf(a.x); o[1] = (short)f2bf(a.y);
    o[2] = (short)f2bf(a.z); o[3] = (short)f2bf(a.w);
    o[4] = (short)f2bf(b.x); o[5] = (short)f2bf(b.y);
    o[6] = (short)f2bf(b.z); o[7] = (short)f2bf(b.w);
    *(bf16x8*)&dst[(size_t)i * 8] = o;
}

// ---- codebook row squared norms (fp32, exact) -------------------------------
__global__ __launch_bounds__(256) void cnorm_kernel(const float* __restrict__ cb,
                                                    float* __restrict__ cnorm) {
    int row  = blockIdx.x * 4 + (threadIdx.x >> 6);
    int lane = threadIdx.x & 63;
    const float* r = cb + (size_t)row * DDIM;
    float s = 0.f;
    #pragma unroll
    for (int d = lane; d < DDIM; d += 64) { float v = r[d]; s += v * v; }
    #pragma unroll
    for (int off = 32; off > 0; off >>= 1) s += __shfl_down(s, off, 64);
    if (lane == 0) cnorm[row] = s;
}

// ---- main: bf16 MFMA scores + margin candidate collection -------------------
// R10: resubmit of R9 (container infra failed twice; no data — 3rd infra flake
// of the session, R1/R6 precedent both ran clean on resubmit).
// R9: T3 "minimum 2-phase" recipe AT 3 blk/CU — the untested matrix cell.
// R2 proved this structure CORRECT (absmax 0) but ran it at 1 blk/CU (96 KB);
// R5 proved the occupancy (3 blk/CU) but with the stage->drain->compute order
// (drain exposed, zero intra-block cover). R8 proved counted-vmcnt/ring +
// sched fences are net-negative (barrier doubling + m141 pin effect).
// R9 = R2's loop shape x R5's occupancy: BK=32 dbuf (2x16 KB + 1K = 33 KB),
//   STAGE(cur^1, t+1);  COMPUTE(cur);  __syncthreads();   // ONE barrier/chunk
// The drain at the barrier is now covered by 16 MFMAs + compiler-hoisted
// interleave (no sched_barrier pins — let the scheduler work, per m141).
// Plain __syncthreads only -> full fence semantics, no race surface.
// Geometry (R5/R8, HW-verified absmax 0): 128 tok x 128 codes, 4 waves 2x2,
// wave 64x64, acc[4][4]=64 AGPR, (256,3) -> 3 blk/CU.
// Swizzle phys_slot = slot ^ ((row>>1)&3): HW-verified (bank conflicts 0).
//
// Block scheduling (L2 locality): 1-D grid of 16384 blocks, decomposed as
//   xcd      = bid & 7          (round-robin XCD heuristic)
//   panel    = (bid>>3) >> 8    cb panel of 1024 codes (1 MB bf16, L2-resident)
//   tb_local = ((bid>>3)&255)>>3, cb_local = (bid>>3)&7  (codes iterate fastest)
__global__ __launch_bounds__(256, 3) void vq_mfma_kernel(
        const unsigned short* __restrict__ zebf,
        const unsigned short* __restrict__ cbbf,
        const float* __restrict__ cnorm,
        int* __restrict__ cnt,
        int* __restrict__ candI,
        float* __restrict__ candS) {
    // LDS rows of 32 bf16 (64 B = 4 slots of 16 B), XOR-swizzled on the
    // global source side (gld16 LDS dest stays linear).
    __shared__ unsigned short Ab[2][128 * 32];   // 2 x 8 KB (tokens x 32 dims)
    __shared__ unsigned short Bb[2][128 * 32];   // 2 x 8 KB (codes  x 32 dims)
    __shared__ float smin[2][128];               // [wc][token_local] cross-wave min

    const int tid  = threadIdx.x;
    const int w    = tid >> 6;
    const int lane = tid & 63;
    const int wr   = w >> 1;          // token half 0..1
    const int wc   = w & 1;           // code  half 0..1

    const int bid      = blockIdx.x;
    const int xcd      = bid & 7;
    const int loc      = bid >> 3;        // 0..2047
    const int panel    = loc >> 8;        // 0..7
    const int l2i      = loc & 255;
    const int tb_local = l2i >> 3;        // 0..31
    const int cb_local = l2i & 7;         // 0..7
    const int token_blk = tb_local * 8 + xcd;     // 0..255
    const int code_blk  = panel * 8 + cb_local;   // 0..63

    const int tok0  = token_blk * 128;
    const int code0 = code_blk * 128;

    // ---- hoisted staging offsets: 2 A + 2 B gld16 per thread per chunk ----
    int ldsOff[2], offA[2], offB[2];
    #pragma unroll
    for (int p = 0; p < 2; ++p) {
        int L    = p * 4096 + tid * 16;   // byte offset in 8 KB buffer, wave-contig
        int row  = L >> 6;                // 64 B per LDS row (32 bf16)
        int phys = (L >> 4) & 3;
        int slog = phys ^ ((row >> 1) & 3);
        ldsOff[p] = L;
        offA[p] = (tok0  + row) * DDIM + slog * 8;   // element offsets (dk added)
        offB[p] = (code0 + row) * DDIM + slog * 8;
    }

    // ---- hoisted fragment element offsets (K=32: slot s0 = lane>>4) ----
    const int s0 = lane >> 4;
    int aOff[4], bOff[4];
    #pragma unroll
    for (int rt = 0; rt < 4; ++rt) {
        int row  = wr * 64 + rt * 16 + (lane & 15);
        aOff[rt] = row * 32 + (s0 ^ ((row >> 1) & 3)) * 8;
    }
    #pragma unroll
    for (int ct = 0; ct < 4; ++ct) {
        int row  = wc * 64 + ct * 16 + (lane & 15);
        bOff[ct] = row * 32 + (s0 ^ ((row >> 1) & 3)) * 8;
    }

    f32x4 acc[4][4];
    const f32x4 zero = {0.f, 0.f, 0.f, 0.f};
    #pragma unroll
    for (int i = 0; i < 4; ++i)
        #pragma unroll
        for (int j = 0; j < 4; ++j) acc[i][j] = zero;

    auto STAGE = [&](int buf, int ck) {
        int dk = ck * 32;
        #pragma unroll
        for (int p = 0; p < 2; ++p) {
            gld16(zebf + (size_t)(offA[p] + dk), (char*)Ab[buf] + ldsOff[p]);
            gld16(cbbf + (size_t)(offB[p] + dk), (char*)Bb[buf] + ldsOff[p]);
        }
    };

    auto COMPUTE = [&](int buf) {
        const unsigned short* A = Ab[buf];
        const unsigned short* B = Bb[buf];
        bf16x8 af[4], bfr[4];
        #pragma unroll
        for (int rt = 0; rt < 4; ++rt) af[rt]  = *(const bf16x8*)(A + aOff[rt]);
        #pragma unroll
        for (int ct = 0; ct < 4; ++ct) bfr[ct] = *(const bf16x8*)(B + bOff[ct]);
        #pragma unroll
        for (int rt = 0; rt < 4; ++rt)
            #pragma unroll
            for (int ct = 0; ct < 4; ++ct)
                acc[rt][ct] = __builtin_amdgcn_mfma_f32_16x16x32_bf16(
                    af[rt], bfr[ct], acc[rt][ct], 0, 0, 0);
    };

    const int NCHUNK = DDIM / 32;   // 16

    STAGE(0, 0);
    __syncthreads();                 // prologue drain: buf0 resident
    int cur = 0;
    #pragma unroll 1
    for (int t = 0; t < NCHUNK - 1; ++t) {
        STAGE(cur ^ 1, t + 1);       // issue next chunk (in flight across compute)
        COMPUTE(cur);                // 16 MFMA cover the load latency
        __syncthreads();             // single drain+fence per chunk (T3 recipe)
        cur ^= 1;
    }
    COMPUTE(cur);                    // last chunk (already drained)

    // ---- epilogue: C/D layout col=lane&15, row=(lane>>4)*4+reg ----
    float cn[4];
    #pragma unroll
    for (int ct = 0; ct < 4; ++ct)
        cn[ct] = cnorm[code0 + wc * 64 + ct * 16 + (lane & 15)];

    // per-wave rowmin over its 64 codes; publish for cross-wave combine
    float rm[4][4];
    #pragma unroll
    for (int rt = 0; rt < 4; ++rt)
        #pragma unroll
        for (int r = 0; r < 4; ++r) {
            float m = cn[0] - 2.f * acc[rt][0][r];
            #pragma unroll
            for (int ct = 1; ct < 4; ++ct)
                m = fminf(m, cn[ct] - 2.f * acc[rt][ct][r]);
            #pragma unroll
            for (int off = 1; off < 16; off <<= 1)
                m = fminf(m, __shfl_xor(m, off, 64));
            rm[rt][r] = m;
            if ((lane & 15) == 0)
                smin[wc][wr * 64 + rt * 16 + (lane >> 4) * 4 + r] = m;
        }
    __syncthreads();

    #pragma unroll
    for (int rt = 0; rt < 4; ++rt)
        #pragma unroll
        for (int r = 0; r < 4; ++r) {
            int tl = wr * 64 + rt * 16 + (lane >> 4) * 4 + r;
            float mo  = smin[1 - wc][tl];               // other code-half's rowmin
            float thr = fminf(rm[rt][r], mo) + MARGIN;  // true 128-code block min
            int token = tok0 + tl;
            #pragma unroll
            for (int ct = 0; ct < 4; ++ct) {
                float s = cn[ct] - 2.f * acc[rt][ct][r];
                if (s <= thr) {
                    int pos = atomicAdd(&cnt[token], 1);
                    if (pos < CAP) {
                        candI[(size_t)token * CAP + pos] = code0 + wc * 64 + ct * 16 + (lane & 15);
                        candS[(size_t)token * CAP + pos] = s;
                    }
                }
            }
        }
}

// ---- exact fp32 rescore of survivors + gather (4 waves per token) -----------
// Candidates split across 4 waves; per-wave (best,idx) combined via LDS with
// the same lexicographic (s, then idx) tie-break. (R8: verified absmax 0.)
__global__ __launch_bounds__(256) void rescore_kernel(
        const float* __restrict__ ze, const float* __restrict__ cb,
        const float* __restrict__ cnorm, const int* __restrict__ cnt,
        const int* __restrict__ candI, const float* __restrict__ candS,
        float* __restrict__ out) {
    const int t    = blockIdx.x;
    const int tid  = threadIdx.x;
    const int v    = tid >> 6;      // wave 0..3
    const int lane = tid & 63;

    __shared__ float sbest[4];
    __shared__ int   sidx[4];

    float4 za = *(const float4*)&ze[(size_t)t * DDIM + lane * 8];
    float4 zb = *(const float4*)&ze[(size_t)t * DDIM + lane * 8 + 4];

    int n = cnt[t];
    bool ovf = (n > CAP) || (n <= 0);

    float best = FLT_MAX;
    int   bidx = 0x7fffffff;

    if (!ovf) {
        // m~ = global min of s~ (every block's true min is in the list);
        // computed redundantly per wave (<= 3 strided passes, cheap).
        float m = FLT_MAX;
        for (int e = lane; e < n; e += 64)
            m = fminf(m, candS[(size_t)t * CAP + e]);
        #pragma unroll
        for (int off = 32; off > 0; off >>= 1)
            m = fminf(m, __shfl_xor(m, off, 64));
        float thr = m + MARGIN;

        for (int base = v * 64; base < n; base += 256) {
            int e = base + lane;
            int myI = 0; float sv = FLT_MAX;
            if (e < n) { myI = candI[(size_t)t * CAP + e]; sv = candS[(size_t)t * CAP + e]; }
            unsigned long long mask = __ballot(e < n && sv <= thr);
            while (mask) {
                int b = __ffsll((long long)mask) - 1;
                mask &= mask - 1;
                int code = __shfl(myI, b, 64);
                const float* row = cb + (size_t)code * DDIM + lane * 8;
                float4 ca = *(const float4*)row;
                float4 cc = *(const float4*)(row + 4);
                float d = za.x*ca.x + za.y*ca.y + za.z*ca.z + za.w*ca.w
                        + zb.x*cc.x + zb.y*cc.y + zb.z*cc.z + zb.w*cc.w;
                #pragma unroll
                for (int off = 32; off > 0; off >>= 1) d += __shfl_xor(d, off, 64);
                float s = cnorm[code] - 2.f * d;
                if (s < best || (s == best && code < bidx)) { best = s; bidx = code; }
            }
        }
    } else {
        for (int code = v; code < KCODES; code += 4) {
            const float* row = cb + (size_t)code * DDIM + lane * 8;
            float4 ca = *(const float4*)row;
            float4 cc = *(const float4*)(row + 4);
            float d = za.x*ca.x + za.y*ca.y + za.z*ca.z + za.w*ca.w
                    + zb.x*cc.x + zb.y*cc.y + zb.z*cc.z + zb.w*cc.w;
            #pragma unroll
            for (int off = 32; off > 0; off >>= 1) d += __shfl_xor(d, off, 64);
            float s = cnorm[code] - 2.f * d;
            if (s < best || (s == best && code < bidx)) { best = s; bidx = code; }
        }
    }

    if (lane == 0) { sbest[v] = best; sidx[v] = bidx; }
    __syncthreads();

    float fb = sbest[0]; int fi = sidx[0];
    #pragma unroll
    for (int k = 1; k < 4; ++k) {
        float s = sbest[k]; int ix = sidx[k];
        if (s < fb || (s == fb && ix < fi)) { fb = s; fi = ix; }
    }

    // gather winner row: 128 threads x float4 = 512 floats
    if (tid < 128) {
        float4 o = *(const float4*)&cb[(size_t)fi * DDIM + tid * 4];
        *(float4*)&out[(size_t)t * DDIM + tid * 4] = o;
    }
}

// ============================ R1 fallback path ===============================
#define TM 64
#define TN 64
#define BK 32
#define LDS_STRIDE (TM + 4)

__global__ __launch_bounds__(256) void vq_fallback_kernel(const float* __restrict__ ze,
                                                          const float* __restrict__ cb,
                                                          const float* __restrict__ cnorm,
                                                          float* __restrict__ out) {
    __shared__ float At[BK][LDS_STRIDE];
    __shared__ float Bt[BK][LDS_STRIDE];
    __shared__ float rv[TM][16];
    __shared__ int   ri[TM][16];
    __shared__ int   best_s[TM];

    const int tid = threadIdx.x;
    const int tx  = tid & 15;
    const int ty  = tid >> 4;
    const int token_base = blockIdx.x * TM;
    const int sc = tid & 31;
    const int sr = tid >> 5;

    float bestv[4] = {FLT_MAX, FLT_MAX, FLT_MAX, FLT_MAX};
    int   besti[4] = {0, 0, 0, 0};

    for (int ctile = 0; ctile < KCODES; ctile += TN) {
        float acc[4][4] = {{0.f}};
        for (int dk = 0; dk < DDIM; dk += BK) {
            __syncthreads();
            #pragma unroll
            for (int p = 0; p < 8; ++p) {
                int r = p * 8 + sr;
                At[sc][r] = ze[(size_t)(token_base + r) * DDIM + dk + sc];
                Bt[sc][r] = cb[(size_t)(ctile + r) * DDIM + dk + sc];
            }
            __syncthreads();
            #pragma unroll
            for (int d = 0; d < BK; ++d) {
                float a[4], b[4];
                *(float4*)a = *(const float4*)&At[d][ty * 4];
                *(float4*)b = *(const float4*)&Bt[d][tx * 4];
                #pragma unroll
                for (int i = 0; i < 4; ++i)
                    #pragma unroll
                    for (int j = 0; j < 4; ++j)
                        acc[i][j] += a[i] * b[j];
            }
        }
        #pragma unroll
        for (int j = 0; j < 4; ++j) {
            int code = ctile + tx * 4 + j;
            float cnv = cnorm[code];
            #pragma unroll
            for (int i = 0; i < 4; ++i) {
                float s = cnv - 2.f * acc[i][j];
                if (s < bestv[i]) { bestv[i] = s; besti[i] = code; }
            }
        }
    }
    #pragma unroll
    for (int i = 0; i < 4; ++i) {
        rv[ty * 4 + i][tx] = bestv[i];
        ri[ty * 4 + i][tx] = besti[i];
    }
    __syncthreads();
    if (tid < TM) {
        float bv = rv[tid][0]; int bi = ri[tid][0];
        #pragma unroll
        for (int x = 1; x < 16; ++x) {
            float v = rv[tid][x]; int ix = ri[tid][x];
            if (v < bv || (v == bv && ix < bi)) { bv = v; bi = ix; }
        }
        best_s[tid] = bi;
    }
    __syncthreads();
    const int gr   = tid >> 7;
    const int gcol = (tid & 127) * 4;
    for (int rr = 0; rr < TM; rr += 2) {
        int tk  = rr + gr;
        int src = best_s[tk];
        float4 v = *(const float4*)&cb[(size_t)src * DDIM + gcol];
        *(float4*)&out[(size_t)(token_base + tk) * DDIM + gcol] = v;
    }
}

extern "C" void kernel_launch(void* const* d_in, const int* in_sizes, int n_in,
                              void* d_out, int out_size, void* d_ws, size_t ws_size,
                              hipStream_t stream) {
    const float* ze = (const float*)d_in[0];   // [32768][512]
    const float* cb = (const float*)d_in[1];   // [8192][512]
    float* out      = (float*)d_out;

    if (ws_size < WS_REQ) {
        // not enough scratch for the MFMA pipeline: R1 exact-fp32 path
        float* cnorm = (float*)d_ws;
        cnorm_kernel<<<KCODES / 4, 256, 0, stream>>>(cb, cnorm);
        vq_fallback_kernel<<<TOKENS / TM, 256, 0, stream>>>(ze, cb, cnorm, out);
        return;
    }

    char* ws = (char*)d_ws;
    unsigned short* zebf = (unsigned short*)(ws + ZEBF_OFF);
    unsigned short* cbbf = (unsigned short*)(ws + CBBF_OFF);
    float* cnorm = (float*)(ws + CNORM_OFF);
    int*   cnt   = (int*)(ws + CNT_OFF);
    int*   candI = (int*)(ws + CANDI_OFF);
    float* candS = (float*)(ws + CANDS_OFF);

    convert_kernel<<<(TOKENS * DDIM / 8) / 256, 256, 0, stream>>>(ze, zebf, TOKENS * DDIM / 8);
    convert_kernel<<<(KCODES * DDIM / 8) / 256, 256, 0, stream>>>(cb, cbbf, KCODES * DDIM / 8);
    cnorm_kernel<<<KCODES / 4, 256, 0, stream>>>(cb, cnorm);
    hipMemsetAsync(cnt, 0, TOKENS * sizeof(int), stream);

    // 1-D grid; block->tile mapping (panel/XCD swizzle) computed in-kernel
    vq_mfma_kernel<<<(TOKENS / 128) * (KCODES / 128), 256, 0, stream>>>(
        zebf, cbbf, cnorm, cnt, candI, candS);

    rescore_kernel<<<TOKENS, 256, 0, stream>>>(ze, cb, cnorm, cnt, candI, candS, out);
}